// Round 2
// baseline (400.074 us; speedup 1.0000x reference)
//
#include <hip/hip_runtime.h>
#include <stdint.h>

#define IN_F   2048
#define OUT_F  2048
#define NROWS  8192   // 4 * 2048
#define BK     64
#define BM     256    // block M tile
#define BN     128    // block N tile
#define NTILES (IN_F / BK)   // 32 K-tiles

typedef __bf16 bf16x8 __attribute__((ext_vector_type(8)));
typedef float  f32x16 __attribute__((ext_vector_type(16)));
typedef unsigned short ushort8v __attribute__((ext_vector_type(8)));

// ---------- helpers ----------

__device__ __forceinline__ unsigned short f2bf_rtne(float f) {
    unsigned int u = __float_as_uint(f);
    u += 0x7FFFu + ((u >> 16) & 1u);   // round-to-nearest-even on bf16 boundary
    return (unsigned short)(u >> 16);
}

__device__ __forceinline__ float softplusf(float v) {
    float a = fabsf(v);
    return fmaxf(v, 0.0f) + log1pf(__expf(-a));
}

// async global->LDS, 16B per lane; LDS dest is wave-uniform base + lane*16
__device__ __forceinline__ void gload_lds16(const void* g, void* l) {
    __builtin_amdgcn_global_load_lds(
        (const __attribute__((address_space(1))) unsigned int*)g,
        (__attribute__((address_space(3))) unsigned int*)l,
        16 /*bytes*/, 0 /*offset*/, 0 /*aux*/);
}

// ---------- prep: fused fp32 -> bf16 conversions into workspace ----------

__global__ __launch_bounds__(256)
void prep_kernel(const float* __restrict__ x, const float* __restrict__ mu,
                 const float* __restrict__ sg,
                 unsigned short* __restrict__ xb, unsigned short* __restrict__ kh,
                 unsigned short* __restrict__ mh) {
    const int b = blockIdx.x;
    const int t = threadIdx.x;
    if (b < 8192) {
        const size_t i = ((size_t)b * 256 + t) * 8;
        float4 v0 = *(const float4*)(x + i);
        float4 v1 = *(const float4*)(x + i + 4);
        ushort8v o;
        o[0] = f2bf_rtne(v0.x); o[1] = f2bf_rtne(v0.y);
        o[2] = f2bf_rtne(v0.z); o[3] = f2bf_rtne(v0.w);
        o[4] = f2bf_rtne(v1.x); o[5] = f2bf_rtne(v1.y);
        o[6] = f2bf_rtne(v1.z); o[7] = f2bf_rtne(v1.w);
        *(ushort8v*)(xb + i) = o;
    } else {
        const size_t i = ((size_t)(b - 8192) * 256 + t) * 8;
        float4 m0 = *(const float4*)(mu + i);
        float4 m1 = *(const float4*)(mu + i + 4);
        float4 s0 = *(const float4*)(sg + i);
        float4 s1 = *(const float4*)(sg + i + 4);
        ushort8v ko, mo;
        ko[0] = f2bf_rtne(m0.x * softplusf(s0.x));
        ko[1] = f2bf_rtne(m0.y * softplusf(s0.y));
        ko[2] = f2bf_rtne(m0.z * softplusf(s0.z));
        ko[3] = f2bf_rtne(m0.w * softplusf(s0.w));
        ko[4] = f2bf_rtne(m1.x * softplusf(s1.x));
        ko[5] = f2bf_rtne(m1.y * softplusf(s1.y));
        ko[6] = f2bf_rtne(m1.z * softplusf(s1.z));
        ko[7] = f2bf_rtne(m1.w * softplusf(s1.w));
        mo[0] = f2bf_rtne(m0.x); mo[1] = f2bf_rtne(m0.y);
        mo[2] = f2bf_rtne(m0.z); mo[3] = f2bf_rtne(m0.w);
        mo[4] = f2bf_rtne(m1.x); mo[5] = f2bf_rtne(m1.y);
        mo[6] = f2bf_rtne(m1.z); mo[7] = f2bf_rtne(m1.w);
        *(ushort8v*)(kh + i) = ko;
        *(ushort8v*)(mh + i) = mo;
    }
}

// ---------- fused double-GEMM, 8-phase-style counted-vmcnt pipeline ----------
// BM=256 x BN=128, BK=64, 8 waves (512 thr), wave tile 64x64 dual-acc sharing
// A-frags. K-tile split into low/high 32-col halves, each a [rows][32] LDS
// sub-tile (64B rows); ring of {AL,AH,BL,BH} x 2 buffers = 128 KB.
// 4 phases per K-tile (one kc each):
//   {6 ds_read_b128 frags(kc) | 2 gload_lds for tile t+1} -> s_barrier ->
//   lgkmcnt(0) -> setprio(1) -> 8 MFMA -> setprio(0) -> [vmcnt(4) at ph1/ph3]
//   -> s_barrier
// Phase p's ds_reads issue under phase p-1's MFMA drain (the overlap the
// 2-phase version lacked). vmcnt(4) counted waits: low(t+1) checked 2.5
// phases after last issue, high(t+1) 3 phases after; drain-0 only in the
// final tile. Chunk swizzle: phys = c ^ ((row>>1)&3), same involution on
// DMA source and ds_read side -> conflict-free per 8-lane phase.

__global__ __launch_bounds__(512, 2)
void gemm_fused_kernel(const unsigned short* __restrict__ xb,  // [8192][2048] bf16
                       const unsigned short* __restrict__ kh,  // [2048][2048] bf16 keys
                       const unsigned short* __restrict__ mh,  // [2048][2048] bf16 mu
                       const float* __restrict__ gate,         // [2048]
                       float* __restrict__ out0,               // masked  [8192][2048]
                       float* __restrict__ out1,               // scores  [8192][2048]
                       float* __restrict__ out2)               // masked  [8192][2048]
{
    // [AL(2x8192) | AH(2x8192) | BL(2x8192: K@0,M@4096) | BH(2x8192)] ushorts
    __shared__ __align__(16) unsigned short lds[65536];   // 128 KB

    const int tid  = threadIdx.x;
    const int lane = tid & 63;
    const int wv   = tid >> 6;

    // XCD-aware bijective swizzle: 512 wgs, 8 XCDs, 64 consecutive wgs/XCD.
    const int swz = (blockIdx.x & 7) * 64 + (blockIdx.x >> 3);
    const int bm  = swz >> 4;    // 0..31 over M panels
    const int bo  = swz & 15;    // 0..15 over N panels

    const int wm = (wv >> 1) * 64;   // wave M offset: 0,64,128,192
    const int wn = (wv & 1) * 64;    // wave N offset: 0,64

    const int fm = lane & 31;
    const int hi = lane >> 5;

    // gate loads first: oldest VMEM ops, retire before any counted wait matters
    const float g0 = gate[bo * BN + wn + fm];
    const float g1 = gate[bo * BN + wn + 32 + fm];

    // ---- staging lane constants (region = 16 rows x 32 cols = 1KB) ----
    // lane covers physical chunk (lane&3) of row (lane>>2) within region;
    // source column = logical chunk = phys ^ ((row>>1)&3) = (lane&3)^((lane>>3)&3)
    const int rr   = lane >> 2;
    const int scol = ((lane & 3) ^ ((lane >> 3) & 3)) * 8;
    const unsigned short* sA0 = xb + (size_t)(bm * BM + wv * 32 + rr) * IN_F + scol;
    const unsigned short* sA1 = sA0 + (size_t)16 * IN_F;
    const unsigned short* sK  = kh + (size_t)(bo * BN + wv * 16 + rr) * IN_F + scol;
    const unsigned short* sM  = mh + (size_t)(bo * BN + wv * 16 + rr) * IN_F + scol;

    // ---- fragment read constants ----
    const int swf   = (fm >> 1) & 3;                 // (row>>1)&3, wm/wn are %32==0
    const int aoff0 = (wm +      fm) * 32;
    const int aoff1 = (wm + 32 + fm) * 32;
    const int boff0 = (wn +      fm) * 32;
    const int boff1 = (wn + 32 + fm) * 32;

    f32x16 accS[2][2], accC[2][2];
#pragma unroll
    for (int i = 0; i < 2; ++i)
#pragma unroll
        for (int j = 0; j < 2; ++j)
#pragma unroll
            for (int r = 0; r < 16; ++r) { accS[i][j][r] = 0.f; accC[i][j][r] = 0.f; }

    // issue the 2 staged gloads belonging to phase p, for tile tt
    auto ISSUE = [&](int p, int tt) {
        const int b2 = tt & 1;
        const int kt = tt * BK;
        switch (p) {
        case 0: {  // A-low: regions 2wv, 2wv+1
            unsigned short* ALb = &lds[b2 * 8192];
            gload_lds16(sA0 + kt, ALb + wv * 1024);
            gload_lds16(sA1 + kt, ALb + wv * 1024 + 512);
            break; }
        case 1: {  // K-low, M-low: region wv each
            unsigned short* BLb = &lds[32768 + b2 * 8192];
            gload_lds16(sK + kt, BLb + wv * 512);
            gload_lds16(sM + kt, BLb + 4096 + wv * 512);
            break; }
        case 2: {  // A-high
            unsigned short* AHb = &lds[16384 + b2 * 8192];
            gload_lds16(sA0 + kt + 32, AHb + wv * 1024);
            gload_lds16(sA1 + kt + 32, AHb + wv * 1024 + 512);
            break; }
        default: { // K-high, M-high
            unsigned short* BHb = &lds[49152 + b2 * 8192];
            gload_lds16(sK + kt + 32, BHb + wv * 512);
            gload_lds16(sM + kt + 32, BHb + 4096 + wv * 512);
            break; }
        }
    };

    // one phase: frags(kc=p) of tile t, optional staging for tile t+1,
    // vmclose: -1 none, 4 counted, 0 drain (last tile only)
    auto PHASE = [&](int t, int p, bool stage, int vmclose) {
        const int b = t & 1;
        const unsigned short* Ah = &lds[(p >= 2 ? 16384 : 0) + b * 8192];
        const unsigned short* Bh = &lds[32768 + (p >= 2 ? 16384 : 0) + b * 8192];
        const int e = (((p & 1) * 2 + hi) ^ swf) * 8;
        bf16x8 a0 = *(const bf16x8*)&Ah[aoff0 + e];
        bf16x8 a1 = *(const bf16x8*)&Ah[aoff1 + e];
        bf16x8 k0 = *(const bf16x8*)&Bh[boff0 + e];
        bf16x8 k1 = *(const bf16x8*)&Bh[boff1 + e];
        bf16x8 m0 = *(const bf16x8*)&Bh[4096 + boff0 + e];
        bf16x8 m1 = *(const bf16x8*)&Bh[4096 + boff1 + e];
        if (stage) ISSUE(p, t + 1);
        __builtin_amdgcn_s_barrier();
        asm volatile("s_waitcnt lgkmcnt(0)" ::: "memory");
        __builtin_amdgcn_sched_barrier(0);
        __builtin_amdgcn_s_setprio(1);
        accS[0][0] = __builtin_amdgcn_mfma_f32_32x32x16_bf16(a0, k0, accS[0][0], 0, 0, 0);
        accS[0][1] = __builtin_amdgcn_mfma_f32_32x32x16_bf16(a0, k1, accS[0][1], 0, 0, 0);
        accS[1][0] = __builtin_amdgcn_mfma_f32_32x32x16_bf16(a1, k0, accS[1][0], 0, 0, 0);
        accS[1][1] = __builtin_amdgcn_mfma_f32_32x32x16_bf16(a1, k1, accS[1][1], 0, 0, 0);
        accC[0][0] = __builtin_amdgcn_mfma_f32_32x32x16_bf16(a0, m0, accC[0][0], 0, 0, 0);
        accC[0][1] = __builtin_amdgcn_mfma_f32_32x32x16_bf16(a0, m1, accC[0][1], 0, 0, 0);
        accC[1][0] = __builtin_amdgcn_mfma_f32_32x32x16_bf16(a1, m0, accC[1][0], 0, 0, 0);
        accC[1][1] = __builtin_amdgcn_mfma_f32_32x32x16_bf16(a1, m1, accC[1][1], 0, 0, 0);
        __builtin_amdgcn_s_setprio(0);
        if (vmclose == 4) asm volatile("s_waitcnt vmcnt(4)" ::: "memory");
        if (vmclose == 0) asm volatile("s_waitcnt vmcnt(0)" ::: "memory");
        __builtin_amdgcn_s_barrier();
        __builtin_amdgcn_sched_barrier(0);
    };

    // ---- prologue: stage tile 0 fully; wait for its low half (oldest 4) ----
#pragma unroll
    for (int p = 0; p < 4; ++p) ISSUE(p, 0);
    asm volatile("s_waitcnt vmcnt(4)" ::: "memory");
    __builtin_amdgcn_s_barrier();
    __builtin_amdgcn_sched_barrier(0);

    // ---- main loop: tiles 0..30, staging t+1; counted vmcnt(4) at ph1/ph3 ----
#pragma unroll 1
    for (int t = 0; t < NTILES - 1; ++t) {
        PHASE(t, 0, true, -1);
        PHASE(t, 1, true, 4);    // guards high(t) for ph2 reads
        PHASE(t, 2, true, -1);
        PHASE(t, 3, true, 4);    // guards low(t+1) for next tile's ph0 reads
    }
    // ---- epilogue tile 31: no staging; drain only where needed ----
    PHASE(NTILES - 1, 0, false, -1);
    PHASE(NTILES - 1, 1, false, 0);   // high(31) must be fully landed
    PHASE(NTILES - 1, 2, false, -1);
    PHASE(NTILES - 1, 3, false, -1);

    // ---- epilogue: 32x32 C/D layout: col=lane&31, row=(reg&3)+8*(reg>>2)+4*hi
    const float inv_sqrt_d = 0.022097086912079608f;  // 1/sqrt(2048)
    const size_t row_base = (size_t)bm * BM + wm;
    const int    col_base = bo * BN + wn;

#pragma unroll
    for (int i = 0; i < 2; ++i) {
#pragma unroll
        for (int j = 0; j < 2; ++j) {
            const float g   = j ? g1 : g0;
            const int   col = col_base + j * 32 + fm;
#pragma unroll
            for (int reg = 0; reg < 16; ++reg) {
                const int ro = (reg & 3) + 8 * (reg >> 2) + 4 * hi;
                const size_t row = row_base + i * 32 + ro;
                const size_t idx = row * OUT_F + col;
                const float s = accS[i][j][reg] * inv_sqrt_d;
                const float c = accC[i][j][reg];
                float w = s - g;
                w = w > 0.f ? w : 0.f;
                const float m = c * w;
                __builtin_nontemporal_store(m, &out0[idx]);
                __builtin_nontemporal_store(s, &out1[idx]);
                __builtin_nontemporal_store(m, &out2[idx]);
            }
        }
    }
}

// ---------- launch ----------

extern "C" void kernel_launch(void* const* d_in, const int* in_sizes, int n_in,
                              void* d_out, int out_size, void* d_ws, size_t ws_size,
                              hipStream_t stream) {
    const float* x    = (const float*)d_in[0];   // [4,2048,2048]
    const float* mu   = (const float*)d_in[1];   // [2048,2048]
    const float* sg   = (const float*)d_in[2];   // [2048,2048]
    const float* gate = (const float*)d_in[3];   // [2048]

    float* out0 = (float*)d_out;                         // final_output
    float* out1 = out0 + (size_t)NROWS * OUT_F;          // scores
    float* out2 = out1 + (size_t)NROWS * OUT_F;          // masked_output

    // workspace layout (bf16): xb 33.55MB | kh 8.39MB | mh 8.39MB  (50.3MB)
    unsigned short* xb = (unsigned short*)d_ws;
    unsigned short* kh = xb + (size_t)NROWS * IN_F;
    unsigned short* mh = kh + (size_t)OUT_F * IN_F;

    prep_kernel<<<8192 + 2048, 256, 0, stream>>>(x, mu, sg, xb, kh, mh);

    dim3 grid(NROWS / BM * (OUT_F / BN));  // 32 * 16 = 512 blocks
    gemm_fused_kernel<<<grid, 512, 0, stream>>>(xb, kh, mh, gate, out0, out1, out2);
}